// Round 1
// baseline (677.086 us; speedup 1.0000x reference)
//
#include <hip/hip_runtime.h>
#include <math.h>

#define B0 32
#define C0 512
#define HW 4096
#define DC 32
#define NS 16
#define RK 32
#define L  512
#define KD 64
#define CB 64          // chunk length for fused middle kernel
#define NCH (L / CB)   // 8 chunks

__device__ __forceinline__ float gelu_exact(float x) {
    return 0.5f * x * (1.0f + erff(x * 0.70710678118654752f));
}
__device__ __forceinline__ float softplus_f(float x) {
    float ax = fabsf(x);
    return fmaxf(x, 0.0f) + log1pf(expf(-ax));
}

// K1: per-(b,c) avg & max over HW=4096
__global__ __launch_bounds__(256) void pool_kernel(const float* __restrict__ x,
                                                   float* __restrict__ avg,
                                                   float* __restrict__ mx) {
    int row = blockIdx.x;  // b*C0 + c
    const float4* xr = (const float4*)(x + (size_t)row * HW);
    int tid = threadIdx.x; // 256
    float s = 0.f, m = -INFINITY;
#pragma unroll
    for (int i = 0; i < 4; ++i) {
        float4 v = xr[tid + i * 256];
        s += v.x + v.y + v.z + v.w;
        m = fmaxf(m, fmaxf(fmaxf(v.x, v.y), fmaxf(v.z, v.w)));
    }
    for (int off = 32; off > 0; off >>= 1) {
        s += __shfl_down(s, off, 64);
        m = fmaxf(m, __shfl_down(m, off, 64));
    }
    __shared__ float ss[4], sm[4];
    int wave = tid >> 6;
    if ((tid & 63) == 0) { ss[wave] = s; sm[wave] = m; }
    __syncthreads();
    if (tid == 0) {
        s = ss[0] + ss[1] + ss[2] + ss[3];
        m = fmaxf(fmaxf(sm[0], sm[1]), fmaxf(sm[2], sm[3]));
        avg[row] = s * (1.0f / HW);
        mx[row] = m;
    }
}

// K2 (fused middle): one block per (b,k). Streams L in NCH chunks of CB:
//   h = gelu(BN(avg*w0+mx*w1))  -> LDS
//   dbl = xcw @ h               -> {sdt, sB, sC} in LDS
//   delta = softplus(dtw @ sdt + dtb) -> LDS
//   single-pass sequential scan (carry in register), n-reduce via shfl,
//   d-reduce in LDS, store per-k y (no atomics, no memset needed).
// All l-coordinates are ORIGINAL; k=1 flip handled by reverse chunk/step order.
__global__ __launch_bounds__(512) void mid_kernel(
    const float* __restrict__ avg, const float* __restrict__ mx,
    const float* __restrict__ w_cin,
    const float* __restrict__ bn_g, const float* __restrict__ bn_b,
    const float* __restrict__ bn_m, const float* __restrict__ bn_v,
    const float* __restrict__ xcw, const float* __restrict__ dtw,
    const float* __restrict__ dtb,
    const float* __restrict__ Ac_logs, const float* __restrict__ Dcs,
    const float* __restrict__ w_cout,
    float* __restrict__ ybl2)   // [B0][2][L]
{
    __shared__ float sW[64 * DC];            // 8 KB  : xc_proj weights (this k)
    __shared__ float sPW[DC * RK];           // 4 KB  : dt proj weights (this k)
    __shared__ float sh_c[DC * (CB + 1)];    // 8.1 KB: h chunk (padded)
    __shared__ float sde[DC * (CB + 1)];     // 8.1 KB: delta chunk (padded)
    __shared__ float sdt[RK * CB];           // 8 KB  : dt raw chunk
    __shared__ float sB[CB * (NS + 1)];      // 4.25KB: B chunk (padded: write stride 16 -> 2-bank)
    __shared__ float sC[CB * (NS + 1)];      // 4.25KB: C chunk
    __shared__ float red[DC * (CB + 1)];     // 8.1 KB: per-d y partials

    int blk = blockIdx.x;          // b*2 + k
    int k = blk & 1;
    int b = blk >> 1;
    int tid = threadIdx.x;         // 512

    for (int i = tid; i < 64 * DC; i += 512) sW[i]  = xcw[k * 64 * DC + i];
    for (int i = tid; i < DC * RK; i += 512) sPW[i] = dtw[k * DC * RK + i];

    int d_s = tid >> 4;            // scan-layout d (0..31)
    int n_s = tid & 15;            // scan-layout n (0..15)
    int kd  = k * DC + d_s;
    float A  = -expf(Ac_logs[kd * NS + n_s]);
    float w  = w_cout[d_s];
    float Dv = Dcs[kd];
    float hs = 0.f;                // scan carry lives here across all chunks

    for (int c = 0; c < NCH; ++c) {
        // chunk's original-l base; k=1 walks chunks (and steps) in reverse l
        int l0 = k ? (L - (c + 1) * CB) : c * CB;
        __syncthreads();           // buffers free (covers weight load on c==0)

        // --- h chunk ---
        for (int i = tid; i < DC * CB; i += 512) {
            int d = i >> 6, ll = i & (CB - 1);
            int gl = l0 + ll;
            float a = avg[b * C0 + gl], m = mx[b * C0 + gl];
            float v = a * w_cin[d * 2] + m * w_cin[d * 2 + 1];
            v = (v - bn_m[d]) * rsqrtf(bn_v[d] + 1e-5f);
            v = v * bn_g[d] + bn_b[d];
            sh_c[d * (CB + 1) + ll] = gelu_exact(v);
        }
        __syncthreads();

        // --- dbl projection -> sdt / sB / sC ---
        for (int idx = tid; idx < 64 * CB; idx += 512) {
            int cc = idx >> 6, ll = idx & (CB - 1);   // cc uniform per wave
            float acc = 0.f;
#pragma unroll
            for (int d = 0; d < DC; ++d) acc += sh_c[d * (CB + 1) + ll] * sW[cc * DC + d];
            if (cc < RK) sdt[cc * CB + ll] = acc;
            else if (cc < RK + NS) sB[ll * (NS + 1) + (cc - RK)] = acc;
            else sC[ll * (NS + 1) + (cc - RK - NS)] = acc;
        }
        __syncthreads();

        // --- delta = softplus(dt proj + bias) ---
        for (int idx = tid; idx < DC * CB; idx += 512) {
            int d = idx >> 6, ll = idx & (CB - 1);
            float acc = dtb[k * DC + d];
#pragma unroll
            for (int r = 0; r < RK; ++r) acc += sdt[r * CB + ll] * sPW[d * RK + r];
            sde[d * (CB + 1) + ll] = softplus_f(acc);
        }
        __syncthreads();

        // --- single-pass scan over this chunk (carry in hs) ---
#pragma unroll 4
        for (int sl = 0; sl < CB; ++sl) {
            int ll = k ? (CB - 1 - sl) : sl;
            float de = sde[d_s * (CB + 1) + ll];
            float u  = sh_c[d_s * (CB + 1) + ll];
            float Bv = sB[ll * (NS + 1) + n_s];
            float Cv = sC[ll * (NS + 1) + n_s];
            hs = expf(de * A) * hs + de * Bv * u;
            float contrib = hs * Cv;
            contrib += __shfl_xor(contrib, 1, 16);
            contrib += __shfl_xor(contrib, 2, 16);
            contrib += __shfl_xor(contrib, 4, 16);
            contrib += __shfl_xor(contrib, 8, 16);
            if (n_s == 0) red[d_s * (CB + 1) + ll] = w * (contrib + Dv * u);
        }
        __syncthreads();

        // --- reduce over d, coalesced store (no atomics) ---
        if (tid < CB) {
            int ll = tid;
            float acc = 0.f;
#pragma unroll
            for (int dd = 0; dd < DC; ++dd) acc += red[dd * (CB + 1) + ll];
            ybl2[(size_t)blk * L + l0 + ll] = acc;
        }
    }
}

// K3: per batch: y = fwd + bwd, gelu + LayerNorm over L -> attn
__global__ __launch_bounds__(512) void epi_kernel(const float* __restrict__ ybl2,
                                                  const float* __restrict__ ln_g,
                                                  const float* __restrict__ ln_b,
                                                  float* __restrict__ attn) {
    int b = blockIdx.x;
    int l = threadIdx.x; // 512
    float y = gelu_exact(ybl2[(size_t)(b * 2) * L + l] + ybl2[(size_t)(b * 2 + 1) * L + l]);
    float s = y, s2 = y * y;
    for (int off = 32; off > 0; off >>= 1) {
        s += __shfl_down(s, off, 64);
        s2 += __shfl_down(s2, off, 64);
    }
    __shared__ float ss[8], ss2[8];
    __shared__ float smu, srv;
    int wave = l >> 6;
    if ((l & 63) == 0) { ss[wave] = s; ss2[wave] = s2; }
    __syncthreads();
    if (l == 0) {
        float ts = 0.f, ts2 = 0.f;
#pragma unroll
        for (int i = 0; i < 8; ++i) { ts += ss[i]; ts2 += ss2[i]; }
        float mu = ts * (1.0f / L);
        float var = ts2 * (1.0f / L) - mu * mu;
        smu = mu;
        srv = rsqrtf(var + 1e-5f);
    }
    __syncthreads();
    attn[b * C0 + l] = (y - smu) * srv * ln_g[l] + ln_b[l];
}

// K4: out = x * (1 + attn[b,c]); 8 float4 per thread, 8192 blocks
__global__ __launch_bounds__(256) void gate_kernel(const float* __restrict__ x,
                                                   const float* __restrict__ attn,
                                                   float* __restrict__ out) {
    const float4* x4 = (const float4*)x;
    float4* o4 = (float4*)out;
    size_t base = (size_t)blockIdx.x * 2048 + threadIdx.x;
#pragma unroll
    for (int i = 0; i < 8; ++i) {
        size_t t = base + (size_t)i * 256;
        float4 v = x4[t];
        float a = 1.0f + attn[t >> 10];   // 1024 float4 per (b,c)
        v.x *= a; v.y *= a; v.z *= a; v.w *= a;
        o4[t] = v;
    }
}

extern "C" void kernel_launch(void* const* d_in, const int* in_sizes, int n_in,
                              void* d_out, int out_size, void* d_ws, size_t ws_size,
                              hipStream_t stream) {
    const float* x     = (const float*)d_in[0];
    const float* xcw   = (const float*)d_in[1];
    const float* dtw   = (const float*)d_in[2];
    const float* dtb   = (const float*)d_in[3];
    const float* Aclog = (const float*)d_in[4];
    const float* Dcs   = (const float*)d_in[5];
    const float* wcin  = (const float*)d_in[6];
    const float* bng   = (const float*)d_in[7];
    const float* bnb   = (const float*)d_in[8];
    const float* bnm   = (const float*)d_in[9];
    const float* bnv   = (const float*)d_in[10];
    const float* wcout = (const float*)d_in[11];
    const float* lng   = (const float*)d_in[12];
    const float* lnb   = (const float*)d_in[13];
    float* out = (float*)d_out;

    float* ws = (float*)d_ws;
    float* avg  = ws;              // 16384
    float* mx   = ws + 16384;      // 16384
    float* ybl2 = ws + 32768;      // 32768 (B0*2*L)
    float* attn = ws + 65536;      // 16384

    pool_kernel<<<B0 * C0, 256, 0, stream>>>(x, avg, mx);
    mid_kernel<<<B0 * 2, 512, 0, stream>>>(avg, mx, wcin, bng, bnb, bnm, bnv,
                                           xcw, dtw, dtb, Aclog, Dcs, wcout, ybl2);
    epi_kernel<<<B0, 512, 0, stream>>>(ybl2, lng, lnb, attn);
    gate_kernel<<<(B0 * C0 * HW / 4) / 2048, 256, 0, stream>>>(x, attn, out);
}

// Round 2
// 583.212 us; speedup vs baseline: 1.1610x; 1.1610x over previous
//
#include <hip/hip_runtime.h>
#include <math.h>

#define B0 32
#define C0 512
#define HW 4096
#define DC 32
#define NS 16
#define RK 32
#define L  512
#define KD 64
#define CB 64          // chunk length
#define NCH (L / CB)   // 8 chunks per (b,k)
#define FSTR 16        // flag stride in ints (cache-line spacing)

#define LOAD_ACQ(p)    __hip_atomic_load((p), __ATOMIC_ACQUIRE, __HIP_MEMORY_SCOPE_AGENT)
#define LOAD_RLX(p)    __hip_atomic_load((p), __ATOMIC_RELAXED, __HIP_MEMORY_SCOPE_AGENT)
#define STORE_RLX(p,v) __hip_atomic_store((p), (v), __ATOMIC_RELAXED, __HIP_MEMORY_SCOPE_AGENT)
#define STORE_REL(p,v) __hip_atomic_store((p), (v), __ATOMIC_RELEASE, __HIP_MEMORY_SCOPE_AGENT)

__device__ __forceinline__ float gelu_exact(float x) {
    return 0.5f * x * (1.0f + erff(x * 0.70710678118654752f));
}
__device__ __forceinline__ float softplus_f(float x) {
    float ax = fabsf(x);
    return fmaxf(x, 0.0f) + log1pf(expf(-ax));
}

// K1: per-(b,c) avg & max over HW=4096
__global__ __launch_bounds__(256) void pool_kernel(const float* __restrict__ x,
                                                   float* __restrict__ avg,
                                                   float* __restrict__ mx) {
    int row = blockIdx.x;  // b*C0 + c
    const float4* xr = (const float4*)(x + (size_t)row * HW);
    int tid = threadIdx.x; // 256
    float s = 0.f, m = -INFINITY;
#pragma unroll
    for (int i = 0; i < 4; ++i) {
        float4 v = xr[tid + i * 256];
        s += v.x + v.y + v.z + v.w;
        m = fmaxf(m, fmaxf(fmaxf(v.x, v.y), fmaxf(v.z, v.w)));
    }
    for (int off = 32; off > 0; off >>= 1) {
        s += __shfl_down(s, off, 64);
        m = fmaxf(m, __shfl_down(m, off, 64));
    }
    __shared__ float ss[4], sm[4];
    int wave = tid >> 6;
    if ((tid & 63) == 0) { ss[wave] = s; sm[wave] = m; }
    __syncthreads();
    if (tid == 0) {
        s = ss[0] + ss[1] + ss[2] + ss[3];
        m = fmaxf(fmaxf(sm[0], sm[1]), fmaxf(sm[2], sm[3]));
        avg[row] = s * (1.0f / HW);
        mx[row] = m;
    }
}

// K2 (fused middle, decoupled look-back): one block per (b,k,chunk).
//   blockIdx = c*64 + (b*2+k)  -> a chain's blocks sit 64 apart => same XCD.
//   proj (h -> dbl -> delta) for own 64-l chunk in LDS,
//   phase A: summary scan (hend per (d,n), sum-delta per d), zero carry,
//   look-back: wait predecessor's inclusive carry (agent-scope atomics),
//              publish own inclusive carry,
//   phase B: full scan from carry, n-reduce (shfl), d-reduce (LDS), store y.
// Capacity-safe: LDS ~45 KB -> 3 blocks/CU; 512 blocks <= 256*3 => all resident.
__global__ __launch_bounds__(512) void mid_kernel(
    const float* __restrict__ avg, const float* __restrict__ mx,
    const float* __restrict__ w_cin,
    const float* __restrict__ bn_g, const float* __restrict__ bn_b,
    const float* __restrict__ bn_m, const float* __restrict__ bn_v,
    const float* __restrict__ xcw, const float* __restrict__ dtw,
    const float* __restrict__ dtb,
    const float* __restrict__ Ac_logs, const float* __restrict__ Dcs,
    const float* __restrict__ w_cout,
    float* __restrict__ carry,   // [64*NCH][DC*NS]
    int* __restrict__ flags,     // [64*NCH][FSTR], pre-zeroed
    float* __restrict__ ybl2)    // [B0][2][L]
{
    __shared__ float sW[64 * DC];            // 8 KB
    __shared__ float sPW[DC * RK];           // 4 KB
    __shared__ float sh_c[DC * (CB + 1)];    // 8.125 KB
    __shared__ float sde[DC * (CB + 1)];     // 8.125 KB
    __shared__ float sdtred[DC * (CB + 1)];  // 8.125 KB (sdt in proj, red in scan)
    __shared__ float sB[CB * (NS + 1)];      // 4.25 KB
    __shared__ float sC[CB * (NS + 1)];      // 4.25 KB

    float* sdt = sdtred;   // [RK][CB] during projection
    float* red = sdtred;   // [DC][CB+1] during scan reduce

    int bk = blockIdx.x & 63;      // b*2 + k
    int c  = blockIdx.x >> 6;      // chunk in scan order
    int k = bk & 1;
    int b = bk >> 1;
    int lidx = bk * NCH + c;       // logical chain position
    int tid = threadIdx.x;         // 512

    for (int i = tid; i < 64 * DC; i += 512) sW[i]  = xcw[k * 64 * DC + i];
    for (int i = tid; i < DC * RK; i += 512) sPW[i] = dtw[k * DC * RK + i];

    // chunk's original-l base; k=1 walks scan order in reverse l
    int l0 = k ? (L - (c + 1) * CB) : c * CB;

    // --- h chunk ---
    for (int i = tid; i < DC * CB; i += 512) {
        int d = i >> 6, ll = i & (CB - 1);
        int gl = l0 + ll;
        float a = avg[b * C0 + gl], m = mx[b * C0 + gl];
        float v = a * w_cin[d * 2] + m * w_cin[d * 2 + 1];
        v = (v - bn_m[d]) * rsqrtf(bn_v[d] + 1e-5f);
        v = v * bn_g[d] + bn_b[d];
        sh_c[d * (CB + 1) + ll] = gelu_exact(v);
    }
    __syncthreads();

    // --- dbl projection -> sdt / sB / sC ---
    for (int idx = tid; idx < 64 * CB; idx += 512) {
        int cc = idx >> 6, ll = idx & (CB - 1);   // cc uniform per wave
        float acc = 0.f;
#pragma unroll
        for (int d = 0; d < DC; ++d) acc += sh_c[d * (CB + 1) + ll] * sW[cc * DC + d];
        if (cc < RK) sdt[cc * CB + ll] = acc;
        else if (cc < RK + NS) sB[ll * (NS + 1) + (cc - RK)] = acc;
        else sC[ll * (NS + 1) + (cc - RK - NS)] = acc;
    }
    __syncthreads();

    // --- delta = softplus(dt proj + bias) ---
    for (int idx = tid; idx < DC * CB; idx += 512) {
        int d = idx >> 6, ll = idx & (CB - 1);
        float acc = dtb[k * DC + d];
#pragma unroll
        for (int r = 0; r < RK; ++r) acc += sdt[r * CB + ll] * sPW[d * RK + r];
        sde[d * (CB + 1) + ll] = softplus_f(acc);
    }
    __syncthreads();

    // --- phase A: local summary scan (zero carry) ---
    int d_s = tid >> 4;
    int n_s = tid & 15;
    int kd  = k * DC + d_s;
    float A = -expf(Ac_logs[kd * NS + n_s]);
    float hloc = 0.f, sdsum = 0.f;
#pragma unroll 4
    for (int sl = 0; sl < CB; ++sl) {
        int ll = k ? (CB - 1 - sl) : sl;
        float de = sde[d_s * (CB + 1) + ll];
        float u  = sh_c[d_s * (CB + 1) + ll];
        float Bv = sB[ll * (NS + 1) + n_s];
        hloc = expf(de * A) * hloc + de * Bv * u;
        sdsum += de;
    }

    // --- look-back: obtain inclusive carry-in, publish carry-out ---
    float cin = 0.f;
    if (c > 0) {
        const int* fprev = flags + (lidx - 1) * FSTR;
        if (tid == 0) {
            while (LOAD_ACQ(fprev) == 0) __builtin_amdgcn_s_sleep(2);
        }
        __syncthreads();
        cin = LOAD_RLX(carry + (size_t)(lidx - 1) * (DC * NS) + tid);
    }
    if (c < NCH - 1) {
        float cout = expf(A * sdsum) * cin + hloc;
        STORE_RLX(carry + (size_t)lidx * (DC * NS) + tid, cout);
        __syncthreads();   // s_waitcnt vmcnt(0) before barrier drains the stores
        if (tid == 0) STORE_REL(flags + lidx * FSTR, 1);
    }

    // --- phase B: full scan from carry, reduce, store ---
    float w  = w_cout[d_s];
    float Dv = Dcs[kd];
    float hs = cin;
#pragma unroll 4
    for (int sl = 0; sl < CB; ++sl) {
        int ll = k ? (CB - 1 - sl) : sl;
        float de = sde[d_s * (CB + 1) + ll];
        float u  = sh_c[d_s * (CB + 1) + ll];
        float Bv = sB[ll * (NS + 1) + n_s];
        float Cv = sC[ll * (NS + 1) + n_s];
        hs = expf(de * A) * hs + de * Bv * u;
        float contrib = hs * Cv;
        contrib += __shfl_xor(contrib, 1, 16);
        contrib += __shfl_xor(contrib, 2, 16);
        contrib += __shfl_xor(contrib, 4, 16);
        contrib += __shfl_xor(contrib, 8, 16);
        if (n_s == 0) red[d_s * (CB + 1) + ll] = w * (contrib + Dv * u);
    }
    __syncthreads();

    if (tid < CB) {
        int ll = tid;
        float acc = 0.f;
#pragma unroll
        for (int dd = 0; dd < DC; ++dd) acc += red[dd * (CB + 1) + ll];
        ybl2[(size_t)bk * L + l0 + ll] = acc;
    }
}

// K3: per batch: y = fwd + bwd, gelu + LayerNorm over L -> attn
__global__ __launch_bounds__(512) void epi_kernel(const float* __restrict__ ybl2,
                                                  const float* __restrict__ ln_g,
                                                  const float* __restrict__ ln_b,
                                                  float* __restrict__ attn) {
    int b = blockIdx.x;
    int l = threadIdx.x; // 512
    float y = gelu_exact(ybl2[(size_t)(b * 2) * L + l] + ybl2[(size_t)(b * 2 + 1) * L + l]);
    float s = y, s2 = y * y;
    for (int off = 32; off > 0; off >>= 1) {
        s += __shfl_down(s, off, 64);
        s2 += __shfl_down(s2, off, 64);
    }
    __shared__ float ss[8], ss2[8];
    __shared__ float smu, srv;
    int wave = l >> 6;
    if ((l & 63) == 0) { ss[wave] = s; ss2[wave] = s2; }
    __syncthreads();
    if (l == 0) {
        float ts = 0.f, ts2 = 0.f;
#pragma unroll
        for (int i = 0; i < 8; ++i) { ts += ss[i]; ts2 += ss2[i]; }
        float mu = ts * (1.0f / L);
        float var = ts2 * (1.0f / L) - mu * mu;
        smu = mu;
        srv = rsqrtf(var + 1e-5f);
    }
    __syncthreads();
    attn[b * C0 + l] = (y - smu) * srv * ln_g[l] + ln_b[l];
}

// K4: out = x * (1 + attn[b,c]); 8 float4 per thread
__global__ __launch_bounds__(256) void gate_kernel(const float* __restrict__ x,
                                                   const float* __restrict__ attn,
                                                   float* __restrict__ out) {
    const float4* x4 = (const float4*)x;
    float4* o4 = (float4*)out;
    size_t base = (size_t)blockIdx.x * 2048 + threadIdx.x;
#pragma unroll
    for (int i = 0; i < 8; ++i) {
        size_t t = base + (size_t)i * 256;
        float4 v = x4[t];
        float a = 1.0f + attn[t >> 10];   // 1024 float4 per (b,c)
        v.x *= a; v.y *= a; v.z *= a; v.w *= a;
        o4[t] = v;
    }
}

extern "C" void kernel_launch(void* const* d_in, const int* in_sizes, int n_in,
                              void* d_out, int out_size, void* d_ws, size_t ws_size,
                              hipStream_t stream) {
    const float* x     = (const float*)d_in[0];
    const float* xcw   = (const float*)d_in[1];
    const float* dtw   = (const float*)d_in[2];
    const float* dtb   = (const float*)d_in[3];
    const float* Aclog = (const float*)d_in[4];
    const float* Dcs   = (const float*)d_in[5];
    const float* wcin  = (const float*)d_in[6];
    const float* bng   = (const float*)d_in[7];
    const float* bnb   = (const float*)d_in[8];
    const float* bnm   = (const float*)d_in[9];
    const float* bnv   = (const float*)d_in[10];
    const float* wcout = (const float*)d_in[11];
    const float* lng   = (const float*)d_in[12];
    const float* lnb   = (const float*)d_in[13];
    float* out = (float*)d_out;

    float* ws = (float*)d_ws;
    float* avg   = ws;                  // 16384
    float* mx    = ws + 16384;          // 16384
    float* ybl2  = ws + 32768;          // 32768 (B0*2*L)
    float* attn  = ws + 65536;          // 16384
    float* carry = ws + 81920;          // 64*NCH*DC*NS = 262144
    int*   flags = (int*)(ws + 344064); // 64*NCH*FSTR = 8192 ints

    pool_kernel<<<B0 * C0, 256, 0, stream>>>(x, avg, mx);
    hipMemsetAsync(flags, 0, (size_t)64 * NCH * FSTR * sizeof(int), stream);
    mid_kernel<<<64 * NCH, 512, 0, stream>>>(avg, mx, wcin, bng, bnb, bnm, bnv,
                                             xcw, dtw, dtb, Aclog, Dcs, wcout,
                                             carry, flags, ybl2);
    epi_kernel<<<B0, 512, 0, stream>>>(ybl2, lng, lnb, attn);
    gate_kernel<<<(B0 * C0 * HW / 4) / 2048, 256, 0, stream>>>(x, attn, out);
}

// Round 3
// 553.088 us; speedup vs baseline: 1.2242x; 1.0545x over previous
//
#include <hip/hip_runtime.h>
#include <math.h>

#define B0 32
#define C0 512
#define HW 4096
#define DC 32
#define NS 16
#define RK 32
#define L  512
#define KD 64
#define CB 64          // chunk length
#define NCH (L / CB)   // 8 chunks per (b,k)
#define NBK 64         // B0*2 chains
#define FSTR 16        // flag stride in ints (cache-line spacing)

#define LOAD_ACQ(p)    __hip_atomic_load((p), __ATOMIC_ACQUIRE, __HIP_MEMORY_SCOPE_AGENT)
#define LOAD_RLX(p)    __hip_atomic_load((p), __ATOMIC_RELAXED, __HIP_MEMORY_SCOPE_AGENT)
#define STORE_RLX(p,v) __hip_atomic_store((p), (v), __ATOMIC_RELAXED, __HIP_MEMORY_SCOPE_AGENT)
#define STORE_REL(p,v) __hip_atomic_store((p), (v), __ATOMIC_RELEASE, __HIP_MEMORY_SCOPE_AGENT)

__device__ __forceinline__ float gelu_exact(float x) {
    return 0.5f * x * (1.0f + erff(x * 0.70710678118654752f));
}
__device__ __forceinline__ float softplus_f(float x) {
    float ax = fabsf(x);
    return fmaxf(x, 0.0f) + log1pf(expf(-ax));
}

// K1: per-(b,c) avg & max over HW=4096. Also zeroes the look-back flags
// (first NBK*NCH blocks) so no separate memset dispatch is needed.
__global__ __launch_bounds__(256) void pool_kernel(const float* __restrict__ x,
                                                   float* __restrict__ avg,
                                                   float* __restrict__ mx,
                                                   int* __restrict__ flags) {
    int row = blockIdx.x;  // b*C0 + c
    if (row < NBK * NCH && threadIdx.x == 0) flags[row * FSTR] = 0;
    const float4* xr = (const float4*)(x + (size_t)row * HW);
    int tid = threadIdx.x; // 256
    float s = 0.f, m = -INFINITY;
#pragma unroll
    for (int i = 0; i < 4; ++i) {
        float4 v = xr[tid + i * 256];
        s += v.x + v.y + v.z + v.w;
        m = fmaxf(m, fmaxf(fmaxf(v.x, v.y), fmaxf(v.z, v.w)));
    }
    for (int off = 32; off > 0; off >>= 1) {
        s += __shfl_down(s, off, 64);
        m = fmaxf(m, __shfl_down(m, off, 64));
    }
    __shared__ float ss[4], sm[4];
    int wave = tid >> 6;
    if ((tid & 63) == 0) { ss[wave] = s; sm[wave] = m; }
    __syncthreads();
    if (tid == 0) {
        s = ss[0] + ss[1] + ss[2] + ss[3];
        m = fmaxf(fmaxf(sm[0], sm[1]), fmaxf(sm[2], sm[3]));
        avg[row] = s * (1.0f / HW);
        mx[row] = m;
    }
}

// K2 (fused middle, ALL-PREDECESSOR look-back): one block per (b,k,chunk).
//   blockIdx = c*NBK + (b*2+k).
//   proj (h -> dbl -> delta) for own 64-l chunk in LDS,
//   phase A: zero-carry summary scan -> publish (hend[d,n], sum-delta[d]) + flag,
//   wait: poll the c predecessor flags (all produced in parallel, depth-1 wait),
//   compose carry locally (<=7 exp+fma per thread),
//   phase B: full scan from carry, n-reduce (shfl), d-reduce (LDS), store y.
// Capacity-safe: LDS ~54 KB -> >=2 blocks/CU; 512 blocks <= 512 resident.
__global__ __launch_bounds__(512) void mid_kernel(
    const float* __restrict__ avg, const float* __restrict__ mx,
    const float* __restrict__ w_cin,
    const float* __restrict__ bn_g, const float* __restrict__ bn_b,
    const float* __restrict__ bn_m, const float* __restrict__ bn_v,
    const float* __restrict__ xcw, const float* __restrict__ dtw,
    const float* __restrict__ dtb,
    const float* __restrict__ Ac_logs, const float* __restrict__ Dcs,
    const float* __restrict__ w_cout,
    float* __restrict__ hendg,   // [NBK*NCH][DC*NS] zero-carry chunk-end states
    float* __restrict__ sdeg,    // [NBK*NCH][DC]    per-chunk sum of delta
    int* __restrict__ flags,     // [NBK*NCH][FSTR]  pre-zeroed by pool
    float* __restrict__ ybl2)    // [B0][2][L]
{
    __shared__ float sW[64 * DC];            // 8 KB
    __shared__ float sPW[DC * RK];           // 4 KB
    __shared__ float sh_c[DC * (CB + 1)];    // 8.125 KB
    __shared__ float sde[DC * (CB + 1)];     // 8.125 KB
    __shared__ float sdtred[DC * (CB + 1)];  // 8.125 KB (sdt in proj, red in scan)
    __shared__ float sB[CB * (NS + 1)];      // 4.25 KB
    __shared__ float sC[CB * (NS + 1)];      // 4.25 KB

    float* sdt = sdtred;   // [RK][CB] during projection
    float* red = sdtred;   // [DC][CB+1] during scan reduce

    int bk = blockIdx.x & (NBK - 1);   // b*2 + k
    int c  = blockIdx.x >> 6;          // chunk in scan order
    int k = bk & 1;
    int b = bk >> 1;
    int base = bk * NCH;
    int lidx = base + c;
    int tid = threadIdx.x;             // 512

    for (int i = tid; i < 64 * DC; i += 512) sW[i]  = xcw[k * 64 * DC + i];
    for (int i = tid; i < DC * RK; i += 512) sPW[i] = dtw[k * DC * RK + i];

    // chunk's original-l base; k=1 walks scan order in reverse l
    int l0 = k ? (L - (c + 1) * CB) : c * CB;

    // --- h chunk ---
    for (int i = tid; i < DC * CB; i += 512) {
        int d = i >> 6, ll = i & (CB - 1);
        int gl = l0 + ll;
        float a = avg[b * C0 + gl], m = mx[b * C0 + gl];
        float v = a * w_cin[d * 2] + m * w_cin[d * 2 + 1];
        v = (v - bn_m[d]) * rsqrtf(bn_v[d] + 1e-5f);
        v = v * bn_g[d] + bn_b[d];
        sh_c[d * (CB + 1) + ll] = gelu_exact(v);
    }
    __syncthreads();

    // --- dbl projection -> sdt / sB / sC ---
    for (int idx = tid; idx < 64 * CB; idx += 512) {
        int cc = idx >> 6, ll = idx & (CB - 1);   // cc uniform per wave
        float acc = 0.f;
#pragma unroll
        for (int d = 0; d < DC; ++d) acc += sh_c[d * (CB + 1) + ll] * sW[cc * DC + d];
        if (cc < RK) sdt[cc * CB + ll] = acc;
        else if (cc < RK + NS) sB[ll * (NS + 1) + (cc - RK)] = acc;
        else sC[ll * (NS + 1) + (cc - RK - NS)] = acc;
    }
    __syncthreads();

    // --- delta = softplus(dt proj + bias) ---
    for (int idx = tid; idx < DC * CB; idx += 512) {
        int d = idx >> 6, ll = idx & (CB - 1);
        float acc = dtb[k * DC + d];
#pragma unroll
        for (int r = 0; r < RK; ++r) acc += sdt[r * CB + ll] * sPW[d * RK + r];
        sde[d * (CB + 1) + ll] = softplus_f(acc);
    }
    __syncthreads();

    // --- phase A: local summary scan (zero carry) ---
    int d_s = tid >> 4;
    int n_s = tid & 15;
    int kd  = k * DC + d_s;
    float A = -expf(Ac_logs[kd * NS + n_s]);
    float hloc = 0.f, sdsum = 0.f;
#pragma unroll 4
    for (int sl = 0; sl < CB; ++sl) {
        int ll = k ? (CB - 1 - sl) : sl;
        float de = sde[d_s * (CB + 1) + ll];
        float u  = sh_c[d_s * (CB + 1) + ll];
        float Bv = sB[ll * (NS + 1) + n_s];
        hloc = expf(de * A) * hloc + de * Bv * u;
        sdsum += de;
    }

    // --- publish own summary FIRST (no waiting before publishing) ---
    if (c < NCH - 1) {
        STORE_RLX(hendg + (size_t)lidx * (DC * NS) + tid, hloc);
        if (n_s == 0) STORE_RLX(sdeg + lidx * DC + d_s, sdsum);
        __syncthreads();   // vmcnt(0) drain: all threads' stores issued to agent scope
        if (tid == 0) STORE_REL(flags + lidx * FSTR, 1);
    }

    // --- wait on ALL predecessors (depth-1 latency), compose carry locally ---
    float cin = 0.f;
    if (c > 0) {
        if (tid < c) {
            const int* fp = flags + (base + tid) * FSTR;
            while (LOAD_ACQ(fp) == 0) __builtin_amdgcn_s_sleep(2);
        }
        __syncthreads();
        for (int j = 0; j < c; ++j) {
            float sd = LOAD_RLX(sdeg + (base + j) * DC + d_s);
            float he = LOAD_RLX(hendg + (size_t)(base + j) * (DC * NS) + tid);
            cin = expf(A * sd) * cin + he;
        }
    }

    // --- phase B: full scan from carry, reduce, store ---
    float w  = w_cout[d_s];
    float Dv = Dcs[kd];
    float hs = cin;
#pragma unroll 4
    for (int sl = 0; sl < CB; ++sl) {
        int ll = k ? (CB - 1 - sl) : sl;
        float de = sde[d_s * (CB + 1) + ll];
        float u  = sh_c[d_s * (CB + 1) + ll];
        float Bv = sB[ll * (NS + 1) + n_s];
        float Cv = sC[ll * (NS + 1) + n_s];
        hs = expf(de * A) * hs + de * Bv * u;
        float contrib = hs * Cv;
        contrib += __shfl_xor(contrib, 1, 16);
        contrib += __shfl_xor(contrib, 2, 16);
        contrib += __shfl_xor(contrib, 4, 16);
        contrib += __shfl_xor(contrib, 8, 16);
        if (n_s == 0) red[d_s * (CB + 1) + ll] = w * (contrib + Dv * u);
    }
    __syncthreads();

    if (tid < CB) {
        int ll = tid;
        float acc = 0.f;
#pragma unroll
        for (int dd = 0; dd < DC; ++dd) acc += red[dd * (CB + 1) + ll];
        ybl2[(size_t)bk * L + l0 + ll] = acc;
    }
}

// K3: per batch: y = fwd + bwd, gelu + LayerNorm over L -> attn
__global__ __launch_bounds__(512) void epi_kernel(const float* __restrict__ ybl2,
                                                  const float* __restrict__ ln_g,
                                                  const float* __restrict__ ln_b,
                                                  float* __restrict__ attn) {
    int b = blockIdx.x;
    int l = threadIdx.x; // 512
    float y = gelu_exact(ybl2[(size_t)(b * 2) * L + l] + ybl2[(size_t)(b * 2 + 1) * L + l]);
    float s = y, s2 = y * y;
    for (int off = 32; off > 0; off >>= 1) {
        s += __shfl_down(s, off, 64);
        s2 += __shfl_down(s2, off, 64);
    }
    __shared__ float ss[8], ss2[8];
    __shared__ float smu, srv;
    int wave = l >> 6;
    if ((l & 63) == 0) { ss[wave] = s; ss2[wave] = s2; }
    __syncthreads();
    if (l == 0) {
        float ts = 0.f, ts2 = 0.f;
#pragma unroll
        for (int i = 0; i < 8; ++i) { ts += ss[i]; ts2 += ss2[i]; }
        float mu = ts * (1.0f / L);
        float var = ts2 * (1.0f / L) - mu * mu;
        smu = mu;
        srv = rsqrtf(var + 1e-5f);
    }
    __syncthreads();
    attn[b * C0 + l] = (y - smu) * srv * ln_g[l] + ln_b[l];
}

// K4: out = x * (1 + attn[b,c]); 8 float4 per thread
__global__ __launch_bounds__(256) void gate_kernel(const float* __restrict__ x,
                                                   const float* __restrict__ attn,
                                                   float* __restrict__ out) {
    const float4* x4 = (const float4*)x;
    float4* o4 = (float4*)out;
    size_t base = (size_t)blockIdx.x * 2048 + threadIdx.x;
#pragma unroll
    for (int i = 0; i < 8; ++i) {
        size_t t = base + (size_t)i * 256;
        float4 v = x4[t];
        float a = 1.0f + attn[t >> 10];   // 1024 float4 per (b,c)
        v.x *= a; v.y *= a; v.z *= a; v.w *= a;
        o4[t] = v;
    }
}

extern "C" void kernel_launch(void* const* d_in, const int* in_sizes, int n_in,
                              void* d_out, int out_size, void* d_ws, size_t ws_size,
                              hipStream_t stream) {
    const float* x     = (const float*)d_in[0];
    const float* xcw   = (const float*)d_in[1];
    const float* dtw   = (const float*)d_in[2];
    const float* dtb   = (const float*)d_in[3];
    const float* Aclog = (const float*)d_in[4];
    const float* Dcs   = (const float*)d_in[5];
    const float* wcin  = (const float*)d_in[6];
    const float* bng   = (const float*)d_in[7];
    const float* bnb   = (const float*)d_in[8];
    const float* bnm   = (const float*)d_in[9];
    const float* bnv   = (const float*)d_in[10];
    const float* wcout = (const float*)d_in[11];
    const float* lng   = (const float*)d_in[12];
    const float* lnb   = (const float*)d_in[13];
    float* out = (float*)d_out;

    float* ws = (float*)d_ws;
    float* avg   = ws;                   // 16384
    float* mx    = ws + 16384;           // 16384
    float* ybl2  = ws + 32768;           // 32768 (B0*2*L)
    float* attn  = ws + 65536;           // 16384
    float* hendg = ws + 81920;           // NBK*NCH*DC*NS = 262144
    float* sdeg  = ws + 344064;          // NBK*NCH*DC    = 16384
    int*   flags = (int*)(ws + 360448);  // NBK*NCH*FSTR  = 8192 ints

    pool_kernel<<<B0 * C0, 256, 0, stream>>>(x, avg, mx, flags);
    mid_kernel<<<NBK * NCH, 512, 0, stream>>>(avg, mx, wcin, bng, bnb, bnm, bnv,
                                              xcw, dtw, dtb, Aclog, Dcs, wcout,
                                              hendg, sdeg, flags, ybl2);
    epi_kernel<<<B0, 512, 0, stream>>>(ybl2, lng, lnb, attn);
    gate_kernel<<<(B0 * C0 * HW / 4) / 2048, 256, 0, stream>>>(x, attn, out);
}

// Round 4
// 538.698 us; speedup vs baseline: 1.2569x; 1.0267x over previous
//
#include <hip/hip_runtime.h>
#include <math.h>

#define B0 32
#define C0 512
#define HW 4096
#define DC 32
#define NS 16
#define RK 32
#define L  512
#define KD 64
#define CB 64          // chunk length
#define NCH (L / CB)   // 8 chunks per (b,k)
#define NBK 64         // B0*2 chains
#define FSTR 16        // flag stride in ints (cache-line spacing)

#define LOAD_ACQ(p)    __hip_atomic_load((p), __ATOMIC_ACQUIRE, __HIP_MEMORY_SCOPE_AGENT)
#define LOAD_RLX(p)    __hip_atomic_load((p), __ATOMIC_RELAXED, __HIP_MEMORY_SCOPE_AGENT)
#define STORE_RLX(p,v) __hip_atomic_store((p), (v), __ATOMIC_RELAXED, __HIP_MEMORY_SCOPE_AGENT)
#define STORE_REL(p,v) __hip_atomic_store((p), (v), __ATOMIC_RELEASE, __HIP_MEMORY_SCOPE_AGENT)

typedef float f32x4 __attribute__((ext_vector_type(4)));

__device__ __forceinline__ float gelu_exact(float x) {
    return 0.5f * x * (1.0f + erff(x * 0.70710678118654752f));
}
__device__ __forceinline__ float softplus_f(float x) {
    float ax = fabsf(x);
    return fmaxf(x, 0.0f) + log1pf(expf(-ax));
}

// K1: per-(b,c) avg & max over HW=4096. Also zeroes look-back flags and
// per-batch epi counters (no separate memset dispatches).
__global__ __launch_bounds__(256) void pool_kernel(const float* __restrict__ x,
                                                   float* __restrict__ avg,
                                                   float* __restrict__ mx,
                                                   int* __restrict__ flags,
                                                   int* __restrict__ cnt) {
    int row = blockIdx.x;  // b*C0 + c
    if (row < NBK * NCH && threadIdx.x == 0) flags[row * FSTR] = 0;
    if (row < B0 && threadIdx.x == 64) cnt[row] = 0;
    const float4* xr = (const float4*)(x + (size_t)row * HW);
    int tid = threadIdx.x; // 256
    float s = 0.f, m = -INFINITY;
#pragma unroll
    for (int i = 0; i < 4; ++i) {
        float4 v = xr[tid + i * 256];
        s += v.x + v.y + v.z + v.w;
        m = fmaxf(m, fmaxf(fmaxf(v.x, v.y), fmaxf(v.z, v.w)));
    }
    for (int off = 32; off > 0; off >>= 1) {
        s += __shfl_down(s, off, 64);
        m = fmaxf(m, __shfl_down(m, off, 64));
    }
    __shared__ float ss[4], sm[4];
    int wave = tid >> 6;
    if ((tid & 63) == 0) { ss[wave] = s; sm[wave] = m; }
    __syncthreads();
    if (tid == 0) {
        s = ss[0] + ss[1] + ss[2] + ss[3];
        m = fmaxf(fmaxf(sm[0], sm[1]), fmaxf(sm[2], sm[3]));
        avg[row] = s * (1.0f / HW);
        mx[row] = m;
    }
}

// K2 (fused middle + epilogue): one block per (b,k,chunk), blockIdx = c*NBK + bk.
//   proj (h -> dbl -> delta) in LDS,
//   phase A: zero-carry summary scan -> publish (hend, sum-delta) + flag,
//   wait on ALL predecessor flags (produced in parallel, depth-1 latency),
//   compose carry locally, phase B full scan, reduce, store y (agent-scope),
//   per-batch completion counter: 16th-finishing block runs gelu+LayerNorm epi.
__global__ __launch_bounds__(512) void mid_kernel(
    const float* __restrict__ avg, const float* __restrict__ mx,
    const float* __restrict__ w_cin,
    const float* __restrict__ bn_g, const float* __restrict__ bn_b,
    const float* __restrict__ bn_m, const float* __restrict__ bn_v,
    const float* __restrict__ xcw, const float* __restrict__ dtw,
    const float* __restrict__ dtb,
    const float* __restrict__ Ac_logs, const float* __restrict__ Dcs,
    const float* __restrict__ w_cout,
    const float* __restrict__ ln_g, const float* __restrict__ ln_b,
    float* __restrict__ hendg,   // [NBK*NCH][DC*NS]
    float* __restrict__ sdeg,    // [NBK*NCH][DC]
    int* __restrict__ flags,     // [NBK*NCH][FSTR] pre-zeroed
    int* __restrict__ cnt,       // [B0] pre-zeroed
    float* __restrict__ ybl2,    // [B0][2][L]
    float* __restrict__ attn)    // [B0][C0]
{
    __shared__ float sW[64 * DC];            // 8 KB
    __shared__ float sPW[DC * RK];           // 4 KB
    __shared__ float sh_c[DC * (CB + 1)];    // 8.125 KB
    __shared__ float sde[DC * (CB + 1)];     // 8.125 KB
    __shared__ float sdtred[DC * (CB + 1)];  // 8.125 KB (sdt in proj, red in scan)
    __shared__ float sB[CB * (NS + 1)];      // 4.25 KB
    __shared__ float sC[CB * (NS + 1)];      // 4.25 KB

    float* sdt = sdtred;
    float* red = sdtred;

    int bk = blockIdx.x & (NBK - 1);   // b*2 + k
    int c  = blockIdx.x >> 6;          // chunk in scan order
    int k = bk & 1;
    int b = bk >> 1;
    int base = bk * NCH;
    int lidx = base + c;
    int tid = threadIdx.x;             // 512

    for (int i = tid; i < 64 * DC; i += 512) sW[i]  = xcw[k * 64 * DC + i];
    for (int i = tid; i < DC * RK; i += 512) sPW[i] = dtw[k * DC * RK + i];

    int l0 = k ? (L - (c + 1) * CB) : c * CB;

    // --- h chunk ---
    for (int i = tid; i < DC * CB; i += 512) {
        int d = i >> 6, ll = i & (CB - 1);
        int gl = l0 + ll;
        float a = avg[b * C0 + gl], m = mx[b * C0 + gl];
        float v = a * w_cin[d * 2] + m * w_cin[d * 2 + 1];
        v = (v - bn_m[d]) * rsqrtf(bn_v[d] + 1e-5f);
        v = v * bn_g[d] + bn_b[d];
        sh_c[d * (CB + 1) + ll] = gelu_exact(v);
    }
    __syncthreads();

    // --- dbl projection -> sdt / sB / sC ---
    for (int idx = tid; idx < 64 * CB; idx += 512) {
        int cc = idx >> 6, ll = idx & (CB - 1);
        float acc = 0.f;
#pragma unroll
        for (int d = 0; d < DC; ++d) acc += sh_c[d * (CB + 1) + ll] * sW[cc * DC + d];
        if (cc < RK) sdt[cc * CB + ll] = acc;
        else if (cc < RK + NS) sB[ll * (NS + 1) + (cc - RK)] = acc;
        else sC[ll * (NS + 1) + (cc - RK - NS)] = acc;
    }
    __syncthreads();

    // --- delta = softplus(dt proj + bias) ---
    for (int idx = tid; idx < DC * CB; idx += 512) {
        int d = idx >> 6, ll = idx & (CB - 1);
        float acc = dtb[k * DC + d];
#pragma unroll
        for (int r = 0; r < RK; ++r) acc += sdt[r * CB + ll] * sPW[d * RK + r];
        sde[d * (CB + 1) + ll] = softplus_f(acc);
    }
    __syncthreads();

    // --- phase A: local summary scan (zero carry) ---
    int d_s = tid >> 4;
    int n_s = tid & 15;
    int kd  = k * DC + d_s;
    float A = -expf(Ac_logs[kd * NS + n_s]);
    float hloc = 0.f, sdsum = 0.f;
#pragma unroll 4
    for (int sl = 0; sl < CB; ++sl) {
        int ll = k ? (CB - 1 - sl) : sl;
        float de = sde[d_s * (CB + 1) + ll];
        float u  = sh_c[d_s * (CB + 1) + ll];
        float Bv = sB[ll * (NS + 1) + n_s];
        hloc = expf(de * A) * hloc + de * Bv * u;
        sdsum += de;
    }

    // --- publish own summary FIRST ---
    if (c < NCH - 1) {
        STORE_RLX(hendg + (size_t)lidx * (DC * NS) + tid, hloc);
        if (n_s == 0) STORE_RLX(sdeg + lidx * DC + d_s, sdsum);
        __syncthreads();   // per-wave vmcnt(0) drain before flag release
        if (tid == 0) STORE_REL(flags + lidx * FSTR, 1);
    }

    // --- wait on ALL predecessors, compose carry locally ---
    float cin = 0.f;
    if (c > 0) {
        if (tid < c) {
            const int* fp = flags + (base + tid) * FSTR;
            while (LOAD_ACQ(fp) == 0) __builtin_amdgcn_s_sleep(2);
        }
        __syncthreads();
        for (int j = 0; j < c; ++j) {
            float sd = LOAD_RLX(sdeg + (base + j) * DC + d_s);
            float he = LOAD_RLX(hendg + (size_t)(base + j) * (DC * NS) + tid);
            cin = expf(A * sd) * cin + he;
        }
    }

    // --- phase B: full scan from carry, reduce, store y ---
    float w  = w_cout[d_s];
    float Dv = Dcs[kd];
    float hs = cin;
#pragma unroll 4
    for (int sl = 0; sl < CB; ++sl) {
        int ll = k ? (CB - 1 - sl) : sl;
        float de = sde[d_s * (CB + 1) + ll];
        float u  = sh_c[d_s * (CB + 1) + ll];
        float Bv = sB[ll * (NS + 1) + n_s];
        float Cv = sC[ll * (NS + 1) + n_s];
        hs = expf(de * A) * hs + de * Bv * u;
        float contrib = hs * Cv;
        contrib += __shfl_xor(contrib, 1, 16);
        contrib += __shfl_xor(contrib, 2, 16);
        contrib += __shfl_xor(contrib, 4, 16);
        contrib += __shfl_xor(contrib, 8, 16);
        if (n_s == 0) red[d_s * (CB + 1) + ll] = w * (contrib + Dv * u);
    }
    __syncthreads();

    if (tid < CB) {
        int ll = tid;
        float acc = 0.f;
#pragma unroll
        for (int dd = 0; dd < DC; ++dd) acc += red[dd * (CB + 1) + ll];
        // agent-scope store: the sibling chain (other k) lives on a different XCD
        STORE_RLX(ybl2 + (size_t)bk * L + l0 + ll, acc);
    }
    __syncthreads();   // drain y stores (per-wave vmcnt(0)) before counter RMW

    // --- per-batch completion counter; 16th block runs the epilogue ---
    __shared__ int isLast;
    if (tid == 0) {
        int old = __hip_atomic_fetch_add(&cnt[b], 1, __ATOMIC_ACQ_REL,
                                         __HIP_MEMORY_SCOPE_AGENT);
        isLast = (old == 2 * NCH - 1);
    }
    __syncthreads();
    if (isLast) {
        int l = tid;  // 512 threads == L
        float y0 = LOAD_RLX(ybl2 + (size_t)(b * 2) * L + l);
        float y1 = LOAD_RLX(ybl2 + (size_t)(b * 2 + 1) * L + l);
        float y = gelu_exact(y0 + y1);
        float s = y, s2 = y * y;
        for (int off = 32; off > 0; off >>= 1) {
            s += __shfl_down(s, off, 64);
            s2 += __shfl_down(s2, off, 64);
        }
        __shared__ float ss[8], ss2[8];
        __shared__ float smu, srv;
        int wave = l >> 6;
        if ((l & 63) == 0) { ss[wave] = s; ss2[wave] = s2; }
        __syncthreads();
        if (l == 0) {
            float ts = 0.f, ts2 = 0.f;
#pragma unroll
            for (int i = 0; i < 8; ++i) { ts += ss[i]; ts2 += ss2[i]; }
            float mu = ts * (1.0f / L);
            float var = ts2 * (1.0f / L) - mu * mu;
            smu = mu;
            srv = rsqrtf(var + 1e-5f);
        }
        __syncthreads();
        attn[b * C0 + l] = (y - smu) * srv * ln_g[l] + ln_b[l];
    }
}

// K3: out = x * (1 + attn[b,c]); REVERSED block order so the L3-resident tail
// of x (just streamed by pool) is consumed first; nontemporal stores so the
// output stream doesn't evict x ahead of the read pointer.
__global__ __launch_bounds__(256) void gate_kernel(const float* __restrict__ x,
                                                   const float* __restrict__ attn,
                                                   float* __restrict__ out) {
    const f32x4* x4 = (const f32x4*)x;
    f32x4* o4 = (f32x4*)out;
    int nblk = (int)gridDim.x;
    int chunk = nblk - 1 - (int)blockIdx.x;   // reversed
    size_t base = (size_t)chunk * 2048 + threadIdx.x;
#pragma unroll
    for (int i = 0; i < 8; ++i) {
        size_t t = base + (size_t)i * 256;
        f32x4 v = x4[t];
        float a = 1.0f + attn[t >> 10];   // 1024 float4 per (b,c)
        v.x *= a; v.y *= a; v.z *= a; v.w *= a;
        __builtin_nontemporal_store(v, &o4[t]);
    }
}

extern "C" void kernel_launch(void* const* d_in, const int* in_sizes, int n_in,
                              void* d_out, int out_size, void* d_ws, size_t ws_size,
                              hipStream_t stream) {
    const float* x     = (const float*)d_in[0];
    const float* xcw   = (const float*)d_in[1];
    const float* dtw   = (const float*)d_in[2];
    const float* dtb   = (const float*)d_in[3];
    const float* Aclog = (const float*)d_in[4];
    const float* Dcs   = (const float*)d_in[5];
    const float* wcin  = (const float*)d_in[6];
    const float* bng   = (const float*)d_in[7];
    const float* bnb   = (const float*)d_in[8];
    const float* bnm   = (const float*)d_in[9];
    const float* bnv   = (const float*)d_in[10];
    const float* wcout = (const float*)d_in[11];
    const float* lng   = (const float*)d_in[12];
    const float* lnb   = (const float*)d_in[13];
    float* out = (float*)d_out;

    float* ws = (float*)d_ws;
    float* avg   = ws;                   // 16384
    float* mx    = ws + 16384;           // 16384
    float* ybl2  = ws + 32768;           // 32768 (B0*2*L)
    float* attn  = ws + 65536;           // 16384
    float* hendg = ws + 81920;           // NBK*NCH*DC*NS = 262144
    float* sdeg  = ws + 344064;          // NBK*NCH*DC    = 16384
    int*   flags = (int*)(ws + 360448);  // NBK*NCH*FSTR  = 8192 ints
    int*   cnt   = flags + NBK * NCH * FSTR; // B0 ints

    pool_kernel<<<B0 * C0, 256, 0, stream>>>(x, avg, mx, flags, cnt);
    mid_kernel<<<NBK * NCH, 512, 0, stream>>>(avg, mx, wcin, bng, bnb, bnm, bnv,
                                              xcw, dtw, dtb, Aclog, Dcs, wcout,
                                              lng, lnb, hendg, sdeg, flags, cnt,
                                              ybl2, attn);
    gate_kernel<<<(B0 * C0 * HW / 4) / 2048, 256, 0, stream>>>(x, attn, out);
}